// Round 4
// baseline (353.248 us; speedup 1.0000x reference)
//
#include <hip/hip_runtime.h>

// SelfAttnHead: B=4, T=2048, E=1024, H=2048. fp32 in/out, bf16 MFMA internally.
// out = softmax_axis1((q q^T / sqrt(H)) * tril) @ v,  q = x Wq + bq, v = x Wv + bv
// attn[q,k] = e[q,k]/s[k], e = exp(masked logits); masked (q<k) entries = exp(0) = 1.
// s[k] = column sum. Fold 1/s into v' = v/s. Triangular decomposition:
//   out[q,h] = sum_{k<K_end} P[q,k] v'[k,h] + sfx[h],  K_end=(rt+1)*256.
// Round 4: the 4-phase/8-barrier K-tile (rounds 1-3, stuck at 30% MfmaUtil)
// serialized LDS-read service (~2300 cyc/CU/tile) against MFMA (~2500 cyc):
// reads-phase -> MFMA-phase alternation for 8 lockstep waves. New K-loop:
// ONE barrier + ONE vmcnt(0) per K-tile. Staging for tile T+1 issues at the
// TOP of tile T, drains at the END (~2500 cyc old -> wait is ~free); within
// the tile no barriers, so the compiler interleaves 24 ds_reads + 64 MFMA
// with counted lgkmcnt and waves free-run (LDS port overlaps matrix pipe).
// LDS layout / staging / swizzle / epilogues byte-identical to the
// refcheck'd round-2/3 kernel. Scores stays on the verified 128^2 kernel.

#define B_DIM 4
#define T_DIM 2048
#define E_DIM 1024
#define H_DIM 2048

typedef __attribute__((ext_vector_type(8))) short bf16x8;
typedef __attribute__((ext_vector_type(4))) short s16x4;
typedef __attribute__((ext_vector_type(4))) float f32x4;

__device__ __forceinline__ float bf2f(short s) {
  union { float f; unsigned u; } x; x.u = ((unsigned)(unsigned short)s) << 16; return x.f;
}
__device__ __forceinline__ short f2bf(float f) {
  union { float f; unsigned u; } x; x.f = f;
  unsigned r = x.u + 0x7fff + ((x.u >> 16) & 1);  // RNE
  return (short)(r >> 16);
}

__device__ __forceinline__ void gload16(const short* g, short* l) {
  __builtin_amdgcn_global_load_lds(
      (const __attribute__((address_space(1))) void*)g,
      (__attribute__((address_space(3))) void*)l, 16, 0, 0);
}

// ============================================================================
// 256x256-tile GEMM:  C[m,n] = sum_k A[m,k]*B[n,k]  (both row-major bf16, K
// contiguous). 512 threads = 8 waves (2M x 4N), per-wave output 128x64.
// BK=64, double-buffered (128 KiB LDS). Per K-tile T:
//   issue 8 global_load_lds for tile T+1 into buf (T+1)&1   (issue-early)
//   kh0: 4 B-frag + 8 A-frag ds_read_b128, 32 MFMA   } compiler-scheduled,
//   kh1: 4 B-frag + 8 A-frag ds_read_b128, 32 MFMA   } no barriers inside
//   s_waitcnt vmcnt(0)   <- loads are a full tile old: ~free
//   s_barrier
// LDS per buf: A[2kh][128 fat][64] | B same (32768 shorts). Fat-line f holds
// rows 2f,2f+1 (4 chunks each): slot = ((r&1)*4 + g) ^ (f&7) — conflict-free
// b128 reads (262K conflicts/dispatch measured).
// MODE 0: dual-output projection, grid (N/256, M/256), XCD-swizzled.
//         ct<8 -> Cg/bias else Cg2/bias2. bf16 out via swizzled LDS repack.
// MODE 2: fp32 out + sfx[2rt+1][col]; K-loop ends at (rt+1)*256.
//         grid (M/256, N/256, B) = 256 blocks, 1/CU, all co-resident.
// ============================================================================
template<int MODE>
__global__ __launch_bounds__(512, 2) void gemm256(
    const short* __restrict__ Ag, const short* __restrict__ Bg,
    const float* __restrict__ bias, const float* __restrict__ bias2,
    void* __restrict__ Cg, void* __restrict__ Cg2,
    const float* __restrict__ sfx,
    int N, int K, long sA, long sB, long sC)
{
  __shared__ __align__(16) short lds[2 * 32768];  // 128 KiB

  const int t = threadIdx.x;
  const int lane = t & 63, wave = t >> 6;
  const int wm = wave >> 2, wn = wave & 3;
  const int l16 = lane & 15, kg = lane >> 4;

  int rt, ct, bz;
  if (MODE == 2) { rt = blockIdx.x; ct = blockIdx.y; bz = blockIdx.z; }
  else {
    // bijective XCD swizzle (nwg = 512, divisible by 8)
    int lin = blockIdx.y * gridDim.x + blockIdx.x;
    const int cpx = (gridDim.x * gridDim.y) >> 3;
    lin = (lin & 7) * cpx + (lin >> 3);
    rt = lin / gridDim.x; ct = lin - rt * gridDim.x;
    bz = 0;
  }

  const short* A  = Ag + (long)bz * sA + (long)rt * 256 * K;
  const short* Bp = Bg + (long)bz * sB + (long)ct * 256 * K;
  const int kEnd = (MODE == 2) ? (rt + 1) * 256 : K;
  const int NT = kEnd >> 6;  // K-tiles of 64 (>= 4 for all uses)

  // staging: per sub (one matrix, one K-half = 8192 shorts), thread t does
  // cid = t and 512+t. f = cid>>3 (fat-line), slot = cid&7, c = slot^(f&7),
  // row = 2f + (c>>2), chunk g = c&3. Dest = cid*8 shorts (lane-contiguous).
  long soff[2];
  int dsto[2];
#pragma unroll
  for (int j = 0; j < 2; ++j) {
    const int cid = j * 512 + t;
    const int f = cid >> 3, sl = cid & 7;
    const int c = sl ^ (f & 7);
    soff[j] = (long)(2 * f + (c >> 2)) * K + (c & 3) * 8;
    dsto[j] = cid * 8;
  }

  // fragment reads: row r, chunk kg within a K-half:
  // f = r>>1, slot = ((r&1)*4 + kg) ^ (f&7); r = base + l16 with base%16==0
  // -> f&7 = (l16>>1)&7. 8-lane groups hit 8 distinct 16B slots (conflict-free).
  const int fl = l16 >> 1;
  const int slot = (((l16 & 1) * 4 + kg) ^ fl) & 7;
  const int aoff = (wm * 64 + fl) * 64 + slot * 8;   // within A K-half
  const int boff = (wn * 32 + fl) * 64 + slot * 8;   // within B K-half

  f32x4 acc[8][4] = {};

  // prologue: stage tile 0 into buf 0 (kh0 A,B then kh1 A,B)
  {
    short* S = lds;
#pragma unroll
    for (int kh = 0; kh < 2; ++kh)
#pragma unroll
      for (int j = 0; j < 2; ++j) {
        gload16(A  + soff[j] + kh * 32, &S[kh * 8192 + dsto[j]]);
        gload16(Bp + soff[j] + kh * 32, &S[16384 + kh * 8192 + dsto[j]]);
      }
  }
  asm volatile("s_waitcnt vmcnt(0)");
  __builtin_amdgcn_sched_barrier(0);
  __builtin_amdgcn_s_barrier();
  __builtin_amdgcn_sched_barrier(0);

  for (int T = 0; T < NT; ++T) {
    const short* Ab = lds + (T & 1) * 32768;   // read buffer
    short* S = lds + ((T + 1) & 1) * 32768;    // write buffer (tile T+1)
    const bool st = (T + 1) < NT;

    // issue-early: stage ALL of tile T+1 now; drained at end of this tile
    if (st) {
      const long kI = (long)(T + 1) * 64;
      gload16(A  + soff[0] + kI, &S[dsto[0]]);
      gload16(A  + soff[1] + kI, &S[dsto[1]]);
      gload16(Bp + soff[0] + kI, &S[16384 + dsto[0]]);
      gload16(Bp + soff[1] + kI, &S[16384 + dsto[1]]);
      gload16(A  + soff[0] + kI + 32, &S[8192 + dsto[0]]);
      gload16(A  + soff[1] + kI + 32, &S[8192 + dsto[1]]);
      gload16(Bp + soff[0] + kI + 32, &S[16384 + 8192 + dsto[0]]);
      gload16(Bp + soff[1] + kI + 32, &S[16384 + 8192 + dsto[1]]);
    }
    __builtin_amdgcn_sched_barrier(0);  // keep stage-issue ahead of compute

    bf16x8 af[8], bfr[4];
    // ---- kh0: full 256-row x 64-col x K=32 ----
#pragma unroll
    for (int n = 0; n < 4; ++n) bfr[n] = *(const bf16x8*)&Ab[16384 + boff + n * 512];
#pragma unroll
    for (int m = 0; m < 8; ++m) af[m] = *(const bf16x8*)&Ab[aoff + m * 512];
    __builtin_amdgcn_s_setprio(1);
#pragma unroll
    for (int m = 0; m < 8; ++m)
#pragma unroll
      for (int n = 0; n < 4; ++n)
        acc[m][n] = __builtin_amdgcn_mfma_f32_16x16x32_bf16(af[m], bfr[n], acc[m][n], 0, 0, 0);
    __builtin_amdgcn_s_setprio(0);
    // ---- kh1 ----
#pragma unroll
    for (int n = 0; n < 4; ++n) bfr[n] = *(const bf16x8*)&Ab[16384 + 8192 + boff + n * 512];
#pragma unroll
    for (int m = 0; m < 8; ++m) af[m] = *(const bf16x8*)&Ab[8192 + aoff + m * 512];
    __builtin_amdgcn_s_setprio(1);
#pragma unroll
    for (int m = 0; m < 8; ++m)
#pragma unroll
      for (int n = 0; n < 4; ++n)
        acc[m][n] = __builtin_amdgcn_mfma_f32_16x16x32_bf16(af[m], bfr[n], acc[m][n], 0, 0, 0);
    __builtin_amdgcn_s_setprio(0);

    if (st) {
      // loads are ~1 full tile old here -> this drain is nearly free
      asm volatile("s_waitcnt vmcnt(0)");
      __builtin_amdgcn_sched_barrier(0);
      __builtin_amdgcn_s_barrier();
      __builtin_amdgcn_sched_barrier(0);
    }
  }

  __syncthreads();  // full drain before LDS reuse / exit

  if (MODE == 0) {
    // repack to bf16 in LDS (256x256 = 128 KiB), row-XOR swizzle so neither
    // the 2B scatter writes nor the b128 row reads 32-way conflict.
    short* Cs = lds;
    const int Nh = N >> 1;
#pragma unroll
    for (int m = 0; m < 8; ++m)
#pragma unroll
      for (int n = 0; n < 4; ++n) {
        const int cl = wn * 64 + n * 16 + l16;
        const int colg = ct * 256 + cl;
        const float bv = (colg < Nh) ? bias[colg] : bias2[colg - Nh];
#pragma unroll
        for (int r = 0; r < 4; ++r) {
          const int rl = wm * 128 + m * 16 + kg * 4 + r;
          *(short*)((char*)Cs + (((((rl << 8) + cl) << 1)) ^ ((rl & 7) << 4))) =
              f2bf(acc[m][n][r] + bv);
        }
      }
    __syncthreads();
    short* C = ((ct * 256) < Nh) ? (short*)Cg : (short*)Cg2;
    const int rr = t >> 1, hc = (t & 1) * 128;
    const long gbase = (long)(rt * 256 + rr) * Nh + ((ct * 256) & (Nh - 1)) + hc;
#pragma unroll
    for (int j = 0; j < 16; ++j)
      *(bf16x8*)(C + gbase + j * 8) =
          *(const bf16x8*)((const char*)Cs +
              ((((rr << 8) + hc + (j << 3)) << 1) ^ ((rr & 7) << 4)));
  } else {
    // fp32 direct stores (64B segments per l16 group) + suffix constant
    float* C = (float*)Cg + (long)bz * sC;
    const float* sf = sfx + ((long)bz * 16 + 2 * rt + 1) * N;
    const int rowb = rt * 256 + wm * 128 + kg * 4;
    const int colb = ct * 256 + wn * 64 + l16;
#pragma unroll
    for (int m = 0; m < 8; ++m)
#pragma unroll
      for (int n = 0; n < 4; ++n) {
        const int col = colb + n * 16;
        const float s = sf[col];
#pragma unroll
        for (int r = 0; r < 4; ++r)
          C[(long)(rowb + m * 16 + r) * N + col] = acc[m][n][r] + s;
      }
  }
}

// ============================================================================
// verified 128^2 kernel, kept for the scores pass (MODE 1)
// ============================================================================
template<int MODE>
__global__ __launch_bounds__(256) void gemm_bt(
    const short* __restrict__ Ag, const short* __restrict__ Bg,
    const float* __restrict__ bias, const float* __restrict__ bias2,
    void* __restrict__ Cg, void* __restrict__ Cg2,
    float* __restrict__ colsum, const float* __restrict__ sfx,
    int M, int N, int K, long sA, long sB, long sC, float scale)
{
  __shared__ __align__(16) short lds[128 * 64 * 2];  // As | Bs; reused as Cs
  short* As = lds;
  short* Bs = lds + 128 * 64;
  __shared__ float csum[128];

  const int t = threadIdx.x;
  const int bz = blockIdx.z;

  int rt, ct;
  if (MODE == 1) {
    int idx = 135 - blockIdx.x;  // heavy (large-rt) tiles dispatch first
    rt = (int)((sqrtf(8.0f * idx + 1.0f) - 1.0f) * 0.5f);
    while ((rt + 1) * (rt + 2) / 2 <= idx) rt++;
    while (rt * (rt + 1) / 2 > idx) rt--;
    ct = idx - rt * (rt + 1) / 2;
  } else {
    rt = blockIdx.y; ct = blockIdx.x;
  }

  const short* A = Ag + (long)bz * sA + (long)rt * 128 * K;
  const short* B = Bg + (long)bz * sB + (long)ct * 128 * K;
  const int kEnd = K;

  const int lane = t & 63;
  const int wave = t >> 6;
  const int wr = wave >> 1, wc = wave & 1;
  const int l16 = lane & 15, kg = lane >> 4;

  if (MODE == 1) { if (t < 128) csum[t] = (rt == ct) ? 128.0f * ct : 0.0f; }

  f32x4 acc[4][4] = {};

  for (int k0 = 0; k0 < kEnd; k0 += 64) {
    __syncthreads();
#pragma unroll
    for (int j = 0; j < 4; ++j) {
      const int e = j * 256 + t;
      const int r = e >> 3, cl = e & 7;
      const int cg = cl ^ (r & 7);
      gload16(A + (long)r * K + (k0 + cg * 8), &As[e * 8]);
      gload16(B + (long)r * K + (k0 + cg * 8), &Bs[e * 8]);
    }
    __syncthreads();
#pragma unroll
    for (int kk = 0; kk < 2; ++kk) {
      bf16x8 af[4], bfr[4];
#pragma unroll
      for (int mi = 0; mi < 4; ++mi)
        af[mi] = *(const bf16x8*)&As[(wr * 64 + mi * 16 + l16) * 64 +
                                     ((kk * 4 + kg) ^ (l16 & 7)) * 8];
#pragma unroll
      for (int ni = 0; ni < 4; ++ni)
        bfr[ni] = *(const bf16x8*)&Bs[(wc * 64 + ni * 16 + l16) * 64 +
                                      ((kk * 4 + kg) ^ (l16 & 7)) * 8];
#pragma unroll
      for (int mi = 0; mi < 4; ++mi)
#pragma unroll
        for (int ni = 0; ni < 4; ++ni)
          acc[mi][ni] = __builtin_amdgcn_mfma_f32_16x16x32_bf16(af[mi], bfr[ni], acc[mi][ni], 0, 0, 0);
    }
  }

  if (MODE == 1) {
    short* Cs = lds;  // 128x128 bf16 tile
    __syncthreads();
    float ps[4] = {0.f, 0.f, 0.f, 0.f};
#pragma unroll
    for (int mi = 0; mi < 4; ++mi)
#pragma unroll
      for (int ni = 0; ni < 4; ++ni) {
        const int cl = wc * 64 + ni * 16 + l16;
        const int col = ct * 128 + cl;
#pragma unroll
        for (int r = 0; r < 4; ++r) {
          const int rl = wr * 64 + kg * 4 + mi * 16 + r;
          const int row = rt * 128 + rl;
          float e = (row >= col) ? __expf(acc[mi][ni][r] * scale) : 1.0f;
          Cs[rl * 128 + cl] = f2bf(e);
          ps[ni] += e;
        }
      }
#pragma unroll
    for (int ni = 0; ni < 4; ++ni)
      atomicAdd(&csum[wc * 64 + ni * 16 + l16], ps[ni]);
    __syncthreads();
    short* C = (short*)Cg + (long)bz * sC;
    const int rr = t >> 1, cc = (t & 1) * 64;
    const long gbase = (long)(rt * 128 + rr) * N + ct * 128 + cc;
#pragma unroll
    for (int j = 0; j < 8; ++j)
      *(bf16x8*)(C + gbase + j * 8) = *(const bf16x8*)&Cs[rr * 128 + cc + j * 8];
    if (t < 128)
      atomicAdd(&colsum[(long)bz * N + ct * 128 + t], csum[t]);
  }
}

// all-ones 128x128 bf16 tiles at (row-tile 2r, col-tile 2r+1) of P: the
// upper-diagonal halves of the PV pass's 256-row tiles (exp(0)=1 entries).
// Their colsum contribution is already in the diag tile's 128*ct seed.
__global__ __launch_bounds__(256) void ones_fill(short* __restrict__ P)
{
  const int r = blockIdx.x, bz = blockIdx.z;
  short* p = P + (long)bz * T_DIM * T_DIM +
             (long)(2 * r) * 128 * T_DIM + (2 * r + 1) * 128;
  const int t = threadIdx.x;
  const int row = t >> 1, c0 = (t & 1) * 64;
  bf16x8 ones;
#pragma unroll
  for (int j = 0; j < 8; ++j) ones[j] = (short)0x3F80;
#pragma unroll
  for (int j = 0; j < 8; ++j)
    *(bf16x8*)(p + (long)row * T_DIM + c0 + j * 8) = ones;
}

// fp32 -> bf16 elementwise (n multiple of 4)
__global__ __launch_bounds__(256) void f32_to_bf16(
    const float* __restrict__ src, short* __restrict__ dst, long n)
{
  long i = ((long)blockIdx.x * blockDim.x + threadIdx.x) * 4;
  if (i < n) {
    const float4 v = *(const float4*)(src + i);
    s16x4 o;
    o.x = f2bf(v.x); o.y = f2bf(v.y); o.z = f2bf(v.z); o.w = f2bf(v.w);
    *(s16x4*)(dst + i) = o;
  }
}

// W transpose: dst[c][r] = src_z[r][c], src fp32 [E,H] -> dst bf16 [H,E].
__global__ __launch_bounds__(256) void wtrans(
    const float* __restrict__ src0, const float* __restrict__ src1,
    short* __restrict__ dst)
{
  __shared__ short tile[64][65];
  const int t = threadIdx.x;
  const int c0 = blockIdx.x * 64;   // over H (dst rows)
  const int r0 = blockIdx.y * 64;   // over E
  const float* s = blockIdx.z ? src1 : src0;
  short* d = dst + (long)blockIdx.z * H_DIM * E_DIM;
  const int rl = t >> 4, cb = (t & 15) * 4;
#pragma unroll
  for (int i = 0; i < 4; ++i) {
    int r = rl + i * 16;
    const float4 w = *(const float4*)(s + (long)(r0 + r) * H_DIM + c0 + cb);
    tile[r][cb + 0] = f2bf(w.x); tile[r][cb + 1] = f2bf(w.y);
    tile[r][cb + 2] = f2bf(w.z); tile[r][cb + 3] = f2bf(w.w);
  }
  __syncthreads();
#pragma unroll
  for (int i = 0; i < 4; ++i) {
    int rr = rl + i * 16;
    s16x4 o;
    o.x = tile[cb + 0][rr]; o.y = tile[cb + 1][rr];
    o.z = tile[cb + 2][rr]; o.w = tile[cb + 3][rr];
    *(s16x4*)(d + (long)(c0 + rr) * E_DIM + r0 + cb) = o;
  }
}

// vT[h][k] = v[k][h] / sums[k]   (v bf16 [T,H] -> vT bf16 [H,T], per batch z)
__global__ __launch_bounds__(256) void vtrans(
    const short* __restrict__ src, short* __restrict__ dst,
    const float* __restrict__ sums)
{
  __shared__ short tile[64][65];
  const int t = threadIdx.x;
  const int c0 = blockIdx.x * 64;   // over H
  const int r0 = blockIdx.y * 64;   // over T (keys)
  const int bz = blockIdx.z;
  const short* s = src + (long)bz * T_DIM * H_DIM;
  short* d = dst + (long)bz * H_DIM * T_DIM;
  const float* su = sums + (long)bz * T_DIM;
  const int rl = t >> 4, cb = (t & 15) * 4;
#pragma unroll
  for (int i = 0; i < 4; ++i) {
    int r = rl + i * 16;
    const float rs = 1.0f / su[r0 + r];
    const s16x4 w = *(const s16x4*)(s + (long)(r0 + r) * H_DIM + c0 + cb);
    tile[r][cb + 0] = f2bf(bf2f(w.x) * rs); tile[r][cb + 1] = f2bf(bf2f(w.y) * rs);
    tile[r][cb + 2] = f2bf(bf2f(w.z) * rs); tile[r][cb + 3] = f2bf(bf2f(w.w) * rs);
  }
  __syncthreads();
#pragma unroll
  for (int i = 0; i < 4; ++i) {
    int rr = rl + i * 16;
    s16x4 o;
    o.x = tile[cb + 0][rr]; o.y = tile[cb + 1][rr];
    o.z = tile[cb + 2][rr]; o.w = tile[cb + 3][rr];
    *(s16x4*)(d + (long)(c0 + rr) * T_DIM + r0 + cb) = o;
  }
}

// psum[bz][j][h2] for 2 h-columns per thread (4B loads)
__global__ __launch_bounds__(256) void block_psum(
    const short* __restrict__ v, const float* __restrict__ colsum,
    float* __restrict__ psum)
{
  const int h = (blockIdx.x * 256 + threadIdx.x) * 2;
  const int j = blockIdx.y, bz = blockIdx.z;
  const short* vb = v + (long)bz * T_DIM * H_DIM;
  const float* cs = colsum + (long)bz * T_DIM;
  float s0 = 0.f, s1 = 0.f;
  const int k0 = j * 128;
  for (int k = k0; k < k0 + 128; ++k) {
    union { int i; short s[2]; } w;
    w.i = *(const int*)(vb + (long)k * H_DIM + h);
    const float rs = 1.0f / cs[k];
    s0 += bf2f(w.s[0]) * rs;
    s1 += bf2f(w.s[1]) * rs;
  }
  float* p = psum + ((long)bz * 16 + j) * H_DIM + h;
  p[0] = s0; p[1] = s1;
}

// sfx[bz][by][h] = sum_{j > by} psum[bz][j][h]
__global__ __launch_bounds__(256) void suffix_scan(
    const float* __restrict__ psum, float* __restrict__ sfx)
{
  const int h = blockIdx.x * 256 + threadIdx.x;
  const int bz = blockIdx.z;
  const long base = (long)bz * 16 * H_DIM + h;
  float suf = 0.f;
  sfx[base + 15L * H_DIM] = 0.f;
  for (int j = 15; j >= 1; --j) {
    suf += psum[base + (long)j * H_DIM];
    sfx[base + (long)(j - 1) * H_DIM] = suf;
  }
}

extern "C" void kernel_launch(void* const* d_in, const int* in_sizes, int n_in,
                              void* d_out, int out_size, void* d_ws, size_t ws_size,
                              hipStream_t stream) {
  const float* x  = (const float*)d_in[0];
  const float* Wq = (const float*)d_in[1];
  const float* bq = (const float*)d_in[2];
  const float* Wv = (const float*)d_in[3];
  const float* bv = (const float*)d_in[4];
  float* out = (float*)d_out;

  // d_ws layout (96 MiB + 544 KiB)
  char* ws = (char*)d_ws;
  short* P      = (short*)(ws);                                   // 32 MiB [B][T][T]
  short* q      = (short*)(ws + (size_t)32 * 1024 * 1024);        // 32 MiB [B*T][H]
  short* v      = (short*)(ws + (size_t)64 * 1024 * 1024);        // 32 MiB [B*T][H]
  float* colsum = (float*)(ws + (size_t)96 * 1024 * 1024);        // 32 KiB [B][T]
  float* sfx    = (float*)(ws + (size_t)96 * 1024 * 1024 + 32 * 1024);  // 512 KiB [B][16][H]
  short* vT = q;  // alias: q dead after the scores GEMM

  // d_out (64 MiB) doubles as scratch; all dead before PV GEMM writes d_out.
  short* xb    = (short*)d_out;                                     // 16 MiB [B*T][E]
  short* WqvT  = (short*)((char*)d_out + (size_t)16 * 1024 * 1024); //  8 MiB [2H][E]
  float* psum  = (float*)((char*)d_out + (size_t)24 * 1024 * 1024); // 512 KiB [B][16][H]

  const float scale = 0.022097086912079612f;  // 1/sqrt(2048)
  dim3 blk(256);

  hipMemsetAsync(colsum, 0, (size_t)B_DIM * T_DIM * 4, stream);

  // x -> bf16; Wq|Wv -> transposed bf16 [2H][E]
  f32_to_bf16<<<dim3((B_DIM * T_DIM * E_DIM) / (256 * 4)), blk, 0, stream>>>(
      x, xb, (long)B_DIM * T_DIM * E_DIM);
  wtrans<<<dim3(H_DIM / 64, E_DIM / 64, 2), blk, 0, stream>>>(Wq, Wv, WqvT);

  // fused projections: [q | v] = x @ WqvT^T + [bq | bv]  (M=8192, N=4096, K=1024)
  gemm256<0><<<dim3((2 * H_DIM) / 256, (B_DIM * T_DIM) / 256, 1), dim3(512), 0, stream>>>(
      xb, WqvT, bq, bv, q, v, nullptr, 2 * H_DIM, E_DIM, 0, 0, 0);

  // E = exp(mask(q q^T)/sqrt(H)): lower-triangular 128-tiles + colsum
  gemm_bt<1><<<dim3(136, 1, B_DIM), blk, 0, stream>>>(
      q, q, nullptr, nullptr, P, nullptr, colsum, nullptr, T_DIM, T_DIM, H_DIM,
      (long)T_DIM * H_DIM, (long)T_DIM * H_DIM, (long)T_DIM * T_DIM, scale);

  // upper-diagonal 128-tiles of the 256-row PV tiles are exp(0)=1
  ones_fill<<<dim3(8, 1, B_DIM), blk, 0, stream>>>(P);

  // vT[h][k] = v[k][h] / colsum[k]; suffix sums of v' over 128-key blocks
  vtrans<<<dim3(H_DIM / 64, T_DIM / 64, B_DIM), blk, 0, stream>>>(v, vT, colsum);
  block_psum<<<dim3(H_DIM / 512, 16, B_DIM), blk, 0, stream>>>(v, colsum, psum);
  suffix_scan<<<dim3(H_DIM / 256, 1, B_DIM), blk, 0, stream>>>(psum, sfx);

  // out = P(:, :K_end) @ v'(:K_end, :) + sfx[2rt+1]   (M=T, N=H, K=T) per batch
  gemm256<2><<<dim3(T_DIM / 256, H_DIM / 256, B_DIM), dim3(512), 0, stream>>>(
      P, vT, nullptr, nullptr, out, nullptr, sfx, H_DIM, T_DIM,
      (long)T_DIM * T_DIM, (long)H_DIM * T_DIM, (long)T_DIM * H_DIM);
}

// Round 5
// 343.094 us; speedup vs baseline: 1.0296x; 1.0296x over previous
//
#include <hip/hip_runtime.h>

// SelfAttnHead: B=4, T=2048, E=1024, H=2048. fp32 in/out, bf16 MFMA internally.
// out = softmax_axis1((q q^T / sqrt(H)) * tril) @ v,  q = x Wq + bq, v = x Wv + bv
// attn[q,k] = e[q,k]/s[k], e = exp(masked logits); masked (q<k) entries = exp(0) = 1.
// s[k] = column sum. Fold 1/s into v' = v/s. Triangular decomposition:
//   out[q,h] = sum_{k<(rt+1)*128} P[q,k] v'[k,h] + sfx[rt][h].
// Round 5: rounds 1-4 showed per-busy-CU GEMM speed is structure-invariant
// (~2370 cyc per 128^2 K-tile across 4 sync skeletons + 2 tile sizes). The
// remaining loss is MAKESPAN: PV's 256 equal-count blocks have work 4..32
// K-tiles (longest job = dispatch duration; avg 18 -> ~45% CU idle). New
// gemm_pv: 128x256 tiles, 512 jobs, heavy-first rt = 15-(lin>>5) -> LPT
// pairing gives CONSTANT 34 K-tiles/CU. Single-buffer m97-style loop (the
// proven structure), 48 KiB LDS, acc64/wave. K_end=(rt+1)*128 (round-0
// semantics) -> upper-ones tiles never read -> ones_fill deleted.
// Proj keeps round-3 gemm256<0>; scores keeps the verified 128^2 kernel.

#define B_DIM 4
#define T_DIM 2048
#define E_DIM 1024
#define H_DIM 2048

typedef __attribute__((ext_vector_type(8))) short bf16x8;
typedef __attribute__((ext_vector_type(4))) short s16x4;
typedef __attribute__((ext_vector_type(4))) float f32x4;

__device__ __forceinline__ float bf2f(short s) {
  union { float f; unsigned u; } x; x.u = ((unsigned)(unsigned short)s) << 16; return x.f;
}
__device__ __forceinline__ short f2bf(float f) {
  union { float f; unsigned u; } x; x.f = f;
  unsigned r = x.u + 0x7fff + ((x.u >> 16) & 1);  // RNE
  return (short)(r >> 16);
}

__device__ __forceinline__ void gload16(const short* g, short* l) {
  __builtin_amdgcn_global_load_lds(
      (const __attribute__((address_space(1))) void*)g,
      (__attribute__((address_space(3))) void*)l, 16, 0, 0);
}

// pure workgroup barrier, no waitcnt drain; sched_barrier pins code motion
__device__ __forceinline__ void bar() {
  __builtin_amdgcn_sched_barrier(0);
  __builtin_amdgcn_s_barrier();
  __builtin_amdgcn_sched_barrier(0);
}

// ============================================================================
// PV GEMM, load-balanced: out[q-tile rt (128 rows), h-tile ct (256 cols)] =
//   P[rt-rows, 0:(rt+1)*128] @ vT[ct-rows, :]^T + sfx[rt].
// 512 threads = 8 waves (2M x 4N), per-wave 64x64 (acc[4][4] = 64 regs).
// Single-buffer BK=64 m97-style loop: sync; stage 6 gloads; sync; compute.
// LDS 48 KiB: A[2kh][128x32] | B[2kh][256x32], fat-line swizzle per region:
// fat-line f = row>>1, slot = ((row&1)*4 + chunk) ^ (f&7) — conflict-free
// b128 frag reads, lane-contiguous gload dest (same formulas as gemm256,
// refcheck'd rounds 2-4).
// Grid dim3(256,2): lin = bx + 256*by; rt = 15-(lin>>5) (heavy-first, lights
// descending -> LPT pairs heavy+light antithetically: 34 K-tiles per CU,
// constant). ct = (lin&31)>>2, bz = lin&3.
// ============================================================================
__global__ __launch_bounds__(512, 2) void gemm_pv(
    const short* __restrict__ Pg, const short* __restrict__ Vg,
    float* __restrict__ Cg, const float* __restrict__ sfx)
{
  __shared__ __align__(16) short lds[24576];  // A: [0,8192) | B: [8192,24576)

  const int t = threadIdx.x;
  const int lane = t & 63, wave = t >> 6;
  const int wm = wave >> 2, wn = wave & 3;
  const int l16 = lane & 15, kg = lane >> 4;

  const int lin = blockIdx.x + 256 * blockIdx.y;
  const int rt = 15 - (lin >> 5);          // 15..0, heavy-first
  const int rem = lin & 31;
  const int ct = rem >> 2, bz = rem & 3;

  const int K = T_DIM, N = H_DIM;
  const short* A  = Pg + (long)bz * T_DIM * T_DIM + (long)rt * 128 * K;
  const short* Bv = Vg + (long)bz * H_DIM * T_DIM + (long)ct * 256 * K;
  const int NT = (rt + 1) * 2;             // K-tiles of 64

  // staging: A region (128 rows x 32 K = 4096 shorts) = 1 gload/kh, cid = t.
  // B region (256 x 32 = 8192 shorts) = 2 gloads/kh, cid = t, 512+t.
  const int fA = t >> 3, cA = (t & 7) ^ (fA & 7);
  const long sA0 = (long)(2 * fA + (cA >> 2)) * K + (cA & 3) * 8;
  const int dA0 = t * 8;
  long sB[2]; int dB[2];
#pragma unroll
  for (int j = 0; j < 2; ++j) {
    const int cid = j * 512 + t;
    const int f = cid >> 3, c = (cid & 7) ^ (f & 7);
    sB[j] = (long)(2 * f + (c >> 2)) * K + (c & 3) * 8;
    dB[j] = cid * 8;
  }

  // fragment reads (same derivation as gemm256): fl = (l16>>1),
  // slot = ((l16&1)*4 + kg) ^ fl; frag row-step 16 -> fat-line step 8.
  const int fl = l16 >> 1;
  const int slot = (((l16 & 1) * 4 + kg) ^ fl) & 7;
  const int abase = (wm * 32 + fl) * 64 + slot * 8;          // A kh-region off
  const int bbase = 8192 + (wn * 32 + fl) * 64 + slot * 8;   // B kh0 base

  f32x4 acc[4][4] = {};

  for (int tt = 0; tt < NT; ++tt) {
    const long k0 = (long)tt * 64;
    __syncthreads();  // all waves done reading previous tile
    gload16(A  + sA0   + k0,      &lds[dA0]);                  // A kh0
    gload16(A  + sA0   + k0 + 32, &lds[4096 + dA0]);           // A kh1
    gload16(Bv + sB[0] + k0,      &lds[8192 + dB[0]]);         // B kh0
    gload16(Bv + sB[1] + k0,      &lds[8192 + dB[1]]);
    gload16(Bv + sB[0] + k0 + 32, &lds[16384 + dB[0]]);        // B kh1
    gload16(Bv + sB[1] + k0 + 32, &lds[16384 + dB[1]]);
    __syncthreads();  // implicit vmcnt(0): staged data landed
#pragma unroll
    for (int kk = 0; kk < 2; ++kk) {
      bf16x8 bfr[4];
#pragma unroll
      for (int ni = 0; ni < 4; ++ni)
        bfr[ni] = *(const bf16x8*)&lds[bbase + kk * 8192 + ni * 512];
#pragma unroll
      for (int mi = 0; mi < 4; ++mi) {
        const bf16x8 a = *(const bf16x8*)&lds[abase + kk * 4096 + mi * 512];
#pragma unroll
        for (int ni = 0; ni < 4; ++ni)
          acc[mi][ni] = __builtin_amdgcn_mfma_f32_16x16x32_bf16(a, bfr[ni], acc[mi][ni], 0, 0, 0);
      }
    }
  }

  // epilogue: fp32 stores (64B segments per l16 group) + suffix constant
  float* C = Cg + (long)bz * T_DIM * H_DIM;
  const float* sf = sfx + ((long)bz * 16 + rt) * N;
  const int rowb = rt * 128 + wm * 64 + kg * 4;
  const int colb = ct * 256 + wn * 64 + l16;
#pragma unroll
  for (int mi = 0; mi < 4; ++mi)
#pragma unroll
    for (int ni = 0; ni < 4; ++ni) {
      const int col = colb + ni * 16;
      const float s = sf[col];
#pragma unroll
      for (int r = 0; r < 4; ++r)
        C[(long)(rowb + mi * 16 + r) * N + col] = acc[mi][ni][r] + s;
    }
}

// ============================================================================
// 256x256-tile 8-phase GEMM (round-3 structure) — used for the projection.
// See round-3 comments; refcheck'd. MODE 0 only this round.
// ============================================================================
template<int MODE>
__global__ __launch_bounds__(512, 2) void gemm256(
    const short* __restrict__ Ag, const short* __restrict__ Bg,
    const float* __restrict__ bias, const float* __restrict__ bias2,
    void* __restrict__ Cg, void* __restrict__ Cg2,
    const float* __restrict__ sfx,
    int N, int K, long sA, long sB, long sC)
{
  __shared__ __align__(16) short lds[2 * 32768];  // 128 KiB

  const int t = threadIdx.x;
  const int lane = t & 63, wave = t >> 6;
  const int wm = wave >> 2, wn = wave & 3;
  const int l16 = lane & 15, kg = lane >> 4;

  int rt, ct, bz;
  {
    // bijective XCD swizzle (nwg = 512, divisible by 8)
    int lin = blockIdx.y * gridDim.x + blockIdx.x;
    const int cpx = (gridDim.x * gridDim.y) >> 3;
    lin = (lin & 7) * cpx + (lin >> 3);
    rt = lin / gridDim.x; ct = lin - rt * gridDim.x;
    bz = 0;
  }

  const short* A  = Ag + (long)bz * sA + (long)rt * 256 * K;
  const short* Bp = Bg + (long)bz * sB + (long)ct * 256 * K;
  const int kEnd = K;
  const int NT = kEnd >> 6;  // K-tiles of 64

  long soff[2];
  int dsto[2];
#pragma unroll
  for (int j = 0; j < 2; ++j) {
    const int cid = j * 512 + t;
    const int f = cid >> 3, sl = cid & 7;
    const int c = sl ^ (f & 7);
    soff[j] = (long)(2 * f + (c >> 2)) * K + (c & 3) * 8;
    dsto[j] = cid * 8;
  }

  const int fl = l16 >> 1;
  const int slot = (((l16 & 1) * 4 + kg) ^ fl) & 7;
  const int aoff = (wm * 64 + fl) * 64 + slot * 8;   // within A K-half
  const int boff = (wn * 32 + fl) * 64 + slot * 8;   // within B K-half

  f32x4 acc[8][4] = {};

  // prologue: stage tile 0 fully
  {
    short* S = lds;
#pragma unroll
    for (int kh = 0; kh < 2; ++kh)
#pragma unroll
      for (int j = 0; j < 2; ++j) {
        gload16(A  + soff[j] + kh * 32, &S[kh * 8192 + dsto[j]]);
        gload16(Bp + soff[j] + kh * 32, &S[16384 + kh * 8192 + dsto[j]]);
      }
  }
  asm volatile("s_waitcnt vmcnt(4)");  // kh0 pair landed
  __builtin_amdgcn_sched_barrier(0);
  bar();

  for (int T = 0; T < NT; ++T) {
    const short* Abase = lds + (T & 1) * 32768;
    short* S = lds + ((T + 1) & 1) * 32768;
    const long kIss = (long)(T + 1) * 64;
    const bool st = (T + 1) < NT;
    bf16x8 bfr[4], af[4];

    // ---- phase s=0: kh0, m0-3 ----
    {
      const short* Ab = Abase;
      const short* Bb = Abase + 16384;
#pragma unroll
      for (int n = 0; n < 4; ++n) bfr[n] = *(const bf16x8*)&Bb[boff + n * 512];
#pragma unroll
      for (int m = 0; m < 4; ++m) af[m] = *(const bf16x8*)&Ab[aoff + m * 512];
      if (st) {
        gload16(A + soff[0] + kIss, &S[dsto[0]]);
        gload16(A + soff[1] + kIss, &S[dsto[1]]);
      }
      bar();
      __builtin_amdgcn_s_setprio(1);
#pragma unroll
      for (int m = 0; m < 4; ++m)
#pragma unroll
        for (int n = 0; n < 4; ++n)
          acc[m][n] = __builtin_amdgcn_mfma_f32_16x16x32_bf16(af[m], bfr[n], acc[m][n], 0, 0, 0);
      __builtin_amdgcn_s_setprio(0);
      bar();
    }
    // ---- phase s=1: kh0, m4-7 ----
    {
      const short* Ab = Abase;
#pragma unroll
      for (int m = 0; m < 4; ++m) af[m] = *(const bf16x8*)&Ab[aoff + (m + 4) * 512];
      if (st) {
        gload16(Bp + soff[0] + kIss, &S[16384 + dsto[0]]);
        gload16(Bp + soff[1] + kIss, &S[16384 + dsto[1]]);
      }
      bar();
      __builtin_amdgcn_s_setprio(1);
#pragma unroll
      for (int m = 0; m < 4; ++m)
#pragma unroll
        for (int n = 0; n < 4; ++n)
          acc[m + 4][n] = __builtin_amdgcn_mfma_f32_16x16x32_bf16(af[m], bfr[n], acc[m + 4][n], 0, 0, 0);
      __builtin_amdgcn_s_setprio(0);
      if (T == NT - 1) asm volatile("s_waitcnt vmcnt(0)");
      else             asm volatile("s_waitcnt vmcnt(4)");
      __builtin_amdgcn_sched_barrier(0);
      bar();
    }
    // ---- phase s=2: kh1, m0-3 ----
    {
      const short* Ab = Abase + 8192;
      const short* Bb = Abase + 16384 + 8192;
#pragma unroll
      for (int n = 0; n < 4; ++n) bfr[n] = *(const bf16x8*)&Bb[boff + n * 512];
#pragma unroll
      for (int m = 0; m < 4; ++m) af[m] = *(const bf16x8*)&Ab[aoff + m * 512];
      if (st) {
        gload16(A + soff[0] + kIss + 32, &S[8192 + dsto[0]]);
        gload16(A + soff[1] + kIss + 32, &S[8192 + dsto[1]]);
      }
      bar();
      __builtin_amdgcn_s_setprio(1);
#pragma unroll
      for (int m = 0; m < 4; ++m)
#pragma unroll
        for (int n = 0; n < 4; ++n)
          acc[m][n] = __builtin_amdgcn_mfma_f32_16x16x32_bf16(af[m], bfr[n], acc[m][n], 0, 0, 0);
      __builtin_amdgcn_s_setprio(0);
      bar();
    }
    // ---- phase s=3: kh1, m4-7 ----
    {
      const short* Ab = Abase + 8192;
#pragma unroll
      for (int m = 0; m < 4; ++m) af[m] = *(const bf16x8*)&Ab[aoff + (m + 4) * 512];
      if (st) {
        gload16(Bp + soff[0] + kIss + 32, &S[16384 + 8192 + dsto[0]]);
        gload16(Bp + soff[1] + kIss + 32, &S[16384 + 8192 + dsto[1]]);
      }
      bar();
      __builtin_amdgcn_s_setprio(1);
#pragma unroll
      for (int m = 0; m < 4; ++m)
#pragma unroll
        for (int n = 0; n < 4; ++n)
          acc[m + 4][n] = __builtin_amdgcn_mfma_f32_16x16x32_bf16(af[m], bfr[n], acc[m + 4][n], 0, 0, 0);
      __builtin_amdgcn_s_setprio(0);
      if (st) {
        asm volatile("s_waitcnt vmcnt(4)");
        __builtin_amdgcn_sched_barrier(0);
      }
      bar();
    }
  }

  __syncthreads();  // full drain before LDS reuse

  // repack to bf16 in LDS (256x256 = 128 KiB), row-XOR swizzle
  {
    short* Cs = lds;
    const int Nh = N >> 1;
#pragma unroll
    for (int m = 0; m < 8; ++m)
#pragma unroll
      for (int n = 0; n < 4; ++n) {
        const int cl = wn * 64 + n * 16 + l16;
        const int colg = ct * 256 + cl;
        const float bv = (colg < Nh) ? bias[colg] : bias2[colg - Nh];
#pragma unroll
        for (int r = 0; r < 4; ++r) {
          const int rl = wm * 128 + m * 16 + kg * 4 + r;
          *(short*)((char*)Cs + (((((rl << 8) + cl) << 1)) ^ ((rl & 7) << 4))) =
              f2bf(acc[m][n][r] + bv);
        }
      }
    __syncthreads();
    short* C = ((ct * 256) < Nh) ? (short*)Cg : (short*)Cg2;
    const int rr = t >> 1, hc = (t & 1) * 128;
    const long gbase = (long)(rt * 256 + rr) * Nh + ((ct * 256) & (Nh - 1)) + hc;
#pragma unroll
    for (int j = 0; j < 16; ++j)
      *(bf16x8*)(C + gbase + j * 8) =
          *(const bf16x8*)((const char*)Cs +
              ((((rr << 8) + hc + (j << 3)) << 1) ^ ((rr & 7) << 4)));
  }
}

// ============================================================================
// verified 128^2 kernel, kept for the scores pass (MODE 1)
// ============================================================================
template<int MODE>
__global__ __launch_bounds__(256) void gemm_bt(
    const short* __restrict__ Ag, const short* __restrict__ Bg,
    const float* __restrict__ bias, const float* __restrict__ bias2,
    void* __restrict__ Cg, void* __restrict__ Cg2,
    float* __restrict__ colsum, const float* __restrict__ sfx,
    int M, int N, int K, long sA, long sB, long sC, float scale)
{
  __shared__ __align__(16) short lds[128 * 64 * 2];  // As | Bs; reused as Cs
  short* As = lds;
  short* Bs = lds + 128 * 64;
  __shared__ float csum[128];

  const int t = threadIdx.x;
  const int bz = blockIdx.z;

  int rt, ct;
  {
    int idx = 135 - blockIdx.x;  // heavy (large-rt) tiles dispatch first
    rt = (int)((sqrtf(8.0f * idx + 1.0f) - 1.0f) * 0.5f);
    while ((rt + 1) * (rt + 2) / 2 <= idx) rt++;
    while (rt * (rt + 1) / 2 > idx) rt--;
    ct = idx - rt * (rt + 1) / 2;
  }

  const short* A = Ag + (long)bz * sA + (long)rt * 128 * K;
  const short* B = Bg + (long)bz * sB + (long)ct * 128 * K;
  const int kEnd = K;

  const int lane = t & 63;
  const int wave = t >> 6;
  const int wr = wave >> 1, wc = wave & 1;
  const int l16 = lane & 15, kg = lane >> 4;

  if (t < 128) csum[t] = (rt == ct) ? 128.0f * ct : 0.0f;

  f32x4 acc[4][4] = {};

  for (int k0 = 0; k0 < kEnd; k0 += 64) {
    __syncthreads();
#pragma unroll
    for (int j = 0; j < 4; ++j) {
      const int e = j * 256 + t;
      const int r = e >> 3, cl = e & 7;
      const int cg = cl ^ (r & 7);
      gload16(A + (long)r * K + (k0 + cg * 8), &As[e * 8]);
      gload16(B + (long)r * K + (k0 + cg * 8), &Bs[e * 8]);
    }
    __syncthreads();
#pragma unroll
    for (int kk = 0; kk < 2; ++kk) {
      bf16x8 af[4], bfr[4];
#pragma unroll
      for (int mi = 0; mi < 4; ++mi)
        af[mi] = *(const bf16x8*)&As[(wr * 64 + mi * 16 + l16) * 64 +
                                     ((kk * 4 + kg) ^ (l16 & 7)) * 8];
#pragma unroll
      for (int ni = 0; ni < 4; ++ni)
        bfr[ni] = *(const bf16x8*)&Bs[(wc * 64 + ni * 16 + l16) * 64 +
                                      ((kk * 4 + kg) ^ (l16 & 7)) * 8];
#pragma unroll
      for (int mi = 0; mi < 4; ++mi)
#pragma unroll
        for (int ni = 0; ni < 4; ++ni)
          acc[mi][ni] = __builtin_amdgcn_mfma_f32_16x16x32_bf16(af[mi], bfr[ni], acc[mi][ni], 0, 0, 0);
    }
  }

  {
    short* Cs = lds;  // 128x128 bf16 tile
    __syncthreads();
    float ps[4] = {0.f, 0.f, 0.f, 0.f};
#pragma unroll
    for (int mi = 0; mi < 4; ++mi)
#pragma unroll
      for (int ni = 0; ni < 4; ++ni) {
        const int cl = wc * 64 + ni * 16 + l16;
        const int col = ct * 128 + cl;
#pragma unroll
        for (int r = 0; r < 4; ++r) {
          const int rl = wr * 64 + kg * 4 + mi * 16 + r;
          const int row = rt * 128 + rl;
          float e = (row >= col) ? __expf(acc[mi][ni][r] * scale) : 1.0f;
          Cs[rl * 128 + cl] = f2bf(e);
          ps[ni] += e;
        }
      }
#pragma unroll
    for (int ni = 0; ni < 4; ++ni)
      atomicAdd(&csum[wc * 64 + ni * 16 + l16], ps[ni]);
    __syncthreads();
    short* C = (short*)Cg + (long)bz * sC;
    const int rr = t >> 1, cc = (t & 1) * 64;
    const long gbase = (long)(rt * 128 + rr) * N + ct * 128 + cc;
#pragma unroll
    for (int j = 0; j < 8; ++j)
      *(bf16x8*)(C + gbase + j * 8) = *(const bf16x8*)&Cs[rr * 128 + cc + j * 8];
    if (t < 128)
      atomicAdd(&colsum[(long)bz * N + ct * 128 + t], csum[t]);
  }
}

// fp32 -> bf16 elementwise (n multiple of 4)
__global__ __launch_bounds__(256) void f32_to_bf16(
    const float* __restrict__ src, short* __restrict__ dst, long n)
{
  long i = ((long)blockIdx.x * blockDim.x + threadIdx.x) * 4;
  if (i < n) {
    const float4 v = *(const float4*)(src + i);
    s16x4 o;
    o.x = f2bf(v.x); o.y = f2bf(v.y); o.z = f2bf(v.z); o.w = f2bf(v.w);
    *(s16x4*)(dst + i) = o;
  }
}

// W transpose: dst[c][r] = src_z[r][c], src fp32 [E,H] -> dst bf16 [H,E].
__global__ __launch_bounds__(256) void wtrans(
    const float* __restrict__ src0, const float* __restrict__ src1,
    short* __restrict__ dst)
{
  __shared__ short tile[64][65];
  const int t = threadIdx.x;
  const int c0 = blockIdx.x * 64;   // over H (dst rows)
  const int r0 = blockIdx.y * 64;   // over E
  const float* s = blockIdx.z ? src1 : src0;
  short* d = dst + (long)blockIdx.z * H_DIM * E_DIM;
  const int rl = t >> 4, cb = (t & 15) * 4;
#pragma unroll
  for (int i = 0; i < 4; ++i) {
    int r = rl + i * 16;
    const float4 w = *(const float4*)(s + (long)(r0 + r) * H_DIM + c0 + cb);
    tile[r][cb + 0] = f2bf(w.x); tile[r][cb + 1] = f2bf(w.y);
    tile[r][cb + 2] = f2bf(w.z); tile[r][cb + 3] = f2bf(w.w);
  }
  __syncthreads();
#pragma unroll
  for (int i = 0; i < 4; ++i) {
    int rr = rl + i * 16;
    s16x4 o;
    o.x = tile[cb + 0][rr]; o.y = tile[cb + 1][rr];
    o.z = tile[cb + 2][rr]; o.w = tile[cb + 3][rr];
    *(s16x4*)(d + (long)(c0 + rr) * E_DIM + r0 + cb) = o;
  }
}

// vT[h][k] = v[k][h] / sums[k]   (v bf16 [T,H] -> vT bf16 [H,T], per batch z)
__global__ __launch_bounds__(256) void vtrans(
    const short* __restrict__ src, short* __restrict__ dst,
    const float* __restrict__ sums)
{
  __shared__ short tile[64][65];
  const int t = threadIdx.x;
  const int c0 = blockIdx.x * 64;   // over H
  const int r0 = blockIdx.y * 64;   // over T (keys)
  const int bz = blockIdx.z;
  const short* s = src + (long)bz * T_DIM * H_DIM;
  short* d = dst + (long)bz * H_DIM * T_DIM;
  const float* su = sums + (long)bz * T_DIM;
  const int rl = t >> 4, cb = (t & 15) * 4;
#pragma unroll
  for (int i = 0; i < 4; ++i) {
    int r = rl + i * 16;
    const float rs = 1.0f / su[r0 + r];
    const s16x4 w = *(const s16x4*)(s + (long)(r0 + r) * H_DIM + c0 + cb);
    tile[r][cb + 0] = f2bf(bf2f(w.x) * rs); tile[r][cb + 1] = f2bf(bf2f(w.y) * rs);
    tile[r][cb + 2] = f2bf(bf2f(w.z) * rs); tile[r][cb + 3] = f2bf(bf2f(w.w) * rs);
  }
  __syncthreads();
#pragma unroll
  for (int i = 0; i < 4; ++i) {
    int rr = rl + i * 16;
    s16x4 o;
    o.x = tile[cb + 0][rr]; o.y = tile[cb + 1][rr];
    o.z = tile[cb + 2][rr]; o.w = tile[cb + 3][rr];
    *(s16x4*)(d + (long)(c0 + rr) * T_DIM + r0 + cb) = o;
  }
}

// psum[bz][j][h2] for 2 h-columns per thread (4B loads)
__global__ __launch_bounds__(256) void block_psum(
    const short* __restrict__ v, const float* __restrict__ colsum,
    float* __restrict__ psum)
{
  const int h = (blockIdx.x * 256 + threadIdx.x) * 2;
  const int j = blockIdx.y, bz = blockIdx.z;
  const short* vb = v + (long)bz * T_DIM * H_DIM;
  const float* cs = colsum + (long)bz * T_DIM;
  float s0 = 0.f, s1 = 0.f;
  const int k0 = j * 128;
  for (int k = k0; k < k0 + 128; ++k) {
    union { int i; short s[2]; } w;
    w.i = *(const int*)(vb + (long)k * H_DIM + h);
    const float rs = 1.0f / cs[k];
    s0 += bf2f(w.s[0]) * rs;
    s1 += bf2f(w.s[1]) * rs;
  }
  float* p = psum + ((long)bz * 16 + j) * H_DIM + h;
  p[0] = s0; p[1] = s1;
}

// sfx[bz][by][h] = sum_{j > by} psum[bz][j][h]
__global__ __launch_bounds__(256) void suffix_scan(
    const float* __restrict__ psum, float* __restrict__ sfx)
{
  const int h = blockIdx.x * 256 + threadIdx.x;
  const int bz = blockIdx.z;
  const long base = (long)bz * 16 * H_DIM + h;
  float suf = 0.f;
  sfx[base + 15L * H_DIM] = 0.f;
  for (int j = 15; j >= 1; --j) {
    suf += psum[base + (long)j * H_DIM];
    sfx[base + (long)(j - 1) * H_DIM] = suf;
  }
}

extern "C" void kernel_launch(void* const* d_in, const int* in_sizes, int n_in,
                              void* d_out, int out_size, void* d_ws, size_t ws_size,
                              hipStream_t stream) {
  const float* x  = (const float*)d_in[0];
  const float* Wq = (const float*)d_in[1];
  const float* bq = (const float*)d_in[2];
  const float* Wv = (const float*)d_in[3];
  const float* bv = (const float*)d_in[4];
  float* out = (float*)d_out;

  // d_ws layout (96 MiB + 544 KiB)
  char* ws = (char*)d_ws;
  short* P      = (short*)(ws);                                   // 32 MiB [B][T][T]
  short* q      = (short*)(ws + (size_t)32 * 1024 * 1024);        // 32 MiB [B*T][H]
  short* v      = (short*)(ws + (size_t)64 * 1024 * 1024);        // 32 MiB [B*T][H]
  float* colsum = (float*)(ws + (size_t)96 * 1024 * 1024);        // 32 KiB [B][T]
  float* sfx    = (float*)(ws + (size_t)96 * 1024 * 1024 + 32 * 1024);  // 512 KiB [B][16][H]
  short* vT = q;  // alias: q dead after the scores GEMM

  // d_out (64 MiB) doubles as scratch; all dead before PV GEMM writes d_out.
  short* xb    = (short*)d_out;                                     // 16 MiB [B*T][E]
  short* WqvT  = (short*)((char*)d_out + (size_t)16 * 1024 * 1024); //  8 MiB [2H][E]
  float* psum  = (float*)((char*)d_out + (size_t)24 * 1024 * 1024); // 512 KiB [B][16][H]

  const float scale = 0.022097086912079612f;  // 1/sqrt(2048)
  dim3 blk(256);

  hipMemsetAsync(colsum, 0, (size_t)B_DIM * T_DIM * 4, stream);

  // x -> bf16; Wq|Wv -> transposed bf16 [2H][E]
  f32_to_bf16<<<dim3((B_DIM * T_DIM * E_DIM) / (256 * 4)), blk, 0, stream>>>(
      x, xb, (long)B_DIM * T_DIM * E_DIM);
  wtrans<<<dim3(H_DIM / 64, E_DIM / 64, 2), blk, 0, stream>>>(Wq, Wv, WqvT);

  // fused projections: [q | v] = x @ WqvT^T + [bq | bv]  (M=8192, N=4096, K=1024)
  gemm256<0><<<dim3((2 * H_DIM) / 256, (B_DIM * T_DIM) / 256, 1), dim3(512), 0, stream>>>(
      xb, WqvT, bq, bv, q, v, nullptr, 2 * H_DIM, E_DIM, 0, 0, 0);

  // E = exp(mask(q q^T)/sqrt(H)): lower-triangular 128-tiles + colsum
  gemm_bt<1><<<dim3(136, 1, B_DIM), blk, 0, stream>>>(
      q, q, nullptr, nullptr, P, nullptr, colsum, nullptr, T_DIM, T_DIM, H_DIM,
      (long)T_DIM * H_DIM, (long)T_DIM * H_DIM, (long)T_DIM * T_DIM, scale);

  // vT[h][k] = v[k][h] / colsum[k]; suffix sums of v' over 128-key blocks
  vtrans<<<dim3(H_DIM / 64, T_DIM / 64, B_DIM), blk, 0, stream>>>(v, vT, colsum);
  block_psum<<<dim3(H_DIM / 512, 16, B_DIM), blk, 0, stream>>>(v, colsum, psum);
  suffix_scan<<<dim3(H_DIM / 256, 1, B_DIM), blk, 0, stream>>>(psum, sfx);

  // out = P(:, :(rt+1)*128) @ v' + sfx[rt]: 512 balanced jobs (34 K-tiles/CU)
  gemm_pv<<<dim3(256, 2, 1), dim3(512), 0, stream>>>(P, vT, out, sfx);
}

// Round 6
// 338.166 us; speedup vs baseline: 1.0446x; 1.0146x over previous
//
#include <hip/hip_runtime.h>

// SelfAttnHead: B=4, T=2048, E=1024, H=2048. fp32 in/out, bf16 MFMA internally.
// out = softmax_axis1((q q^T / sqrt(H)) * tril) @ v,  q = x Wq + bq, v = x Wv + bv
// attn[q,k] = e[q,k]/s[k], e = exp(masked logits); masked (q<k) entries = exp(0) = 1.
// s[k] = column sum. Fold 1/s into v' = v/s. Triangular decomposition:
//   out[q,h] = sum_{k<(rt+1)*128} P[q,k] v'[k,h] + sum_{j>rt} psum[j][h].
// Round 6: dispatch-graph surgery (schedule-level wins only; GEMM cores are
// round-5-verified and untouched):
//  - prep = f32_to_bf16 + wtrans + colsum/psum zeroing (1 launch, was 3)
//  - block_psum folded into vtrans (LDS column-reduce + global atomicAdd;
//    also removes a 32 MiB re-read of v)
//  - suffix_scan folded into gemm_pv epilogue (on-the-fly suffix over psum,
//    uniform-bound loop, L2-resident)
// Launches 9 -> 5. psum lives in d_ws (PV overwrites all of d_out).

#define B_DIM 4
#define T_DIM 2048
#define E_DIM 1024
#define H_DIM 2048

typedef __attribute__((ext_vector_type(8))) short bf16x8;
typedef __attribute__((ext_vector_type(4))) short s16x4;
typedef __attribute__((ext_vector_type(4))) float f32x4;

__device__ __forceinline__ float bf2f(short s) {
  union { float f; unsigned u; } x; x.u = ((unsigned)(unsigned short)s) << 16; return x.f;
}
__device__ __forceinline__ short f2bf(float f) {
  union { float f; unsigned u; } x; x.f = f;
  unsigned r = x.u + 0x7fff + ((x.u >> 16) & 1);  // RNE
  return (short)(r >> 16);
}

__device__ __forceinline__ void gload16(const short* g, short* l) {
  __builtin_amdgcn_global_load_lds(
      (const __attribute__((address_space(1))) void*)g,
      (__attribute__((address_space(3))) void*)l, 16, 0, 0);
}

// pure workgroup barrier, no waitcnt drain; sched_barrier pins code motion
__device__ __forceinline__ void bar() {
  __builtin_amdgcn_sched_barrier(0);
  __builtin_amdgcn_s_barrier();
  __builtin_amdgcn_sched_barrier(0);
}

// ============================================================================
// prep: blocks [0, 8192): x fp32 -> xb bf16 (4 elems/thread); also zeroes
//       colsum (8192 floats) and psum (131072 floats).
//       blocks [8192, 9216): W transpose, dst[c][r] = (z? Wv : Wq)[r][c] bf16.
// ============================================================================
#define NCONV 8192
__global__ __launch_bounds__(256) void prep(
    const float* __restrict__ x, short* __restrict__ xb,
    const float* __restrict__ Wq, const float* __restrict__ Wv,
    short* __restrict__ WqvT, float* __restrict__ colsum,
    float* __restrict__ psum)
{
  __shared__ short tile[64][65];
  const int b = blockIdx.x;
  const int t = threadIdx.x;
  if (b < NCONV) {
    const long tid = (long)b * 256 + t;
    const long i = tid * 4;
    const float4 v = *(const float4*)(x + i);
    s16x4 o;
    o.x = f2bf(v.x); o.y = f2bf(v.y); o.z = f2bf(v.z); o.w = f2bf(v.w);
    *(s16x4*)(xb + i) = o;
    if (tid < B_DIM * T_DIM) colsum[tid] = 0.f;
    if (tid < (long)B_DIM * 16 * H_DIM) psum[tid] = 0.f;
  } else {
    int id = b - NCONV;
    const int z = id >> 9;  // 512 blocks per matrix
    id &= 511;
    const int c0 = (id & 31) * 64;   // over H (dst rows)
    const int r0 = (id >> 5) * 64;   // over E
    const float* s = z ? Wv : Wq;
    short* d = WqvT + (long)z * H_DIM * E_DIM;
    const int rl = t >> 4, cb = (t & 15) * 4;
#pragma unroll
    for (int i = 0; i < 4; ++i) {
      int r = rl + i * 16;
      const float4 w = *(const float4*)(s + (long)(r0 + r) * H_DIM + c0 + cb);
      tile[r][cb + 0] = f2bf(w.x); tile[r][cb + 1] = f2bf(w.y);
      tile[r][cb + 2] = f2bf(w.z); tile[r][cb + 3] = f2bf(w.w);
    }
    __syncthreads();
#pragma unroll
    for (int i = 0; i < 4; ++i) {
      int rr = rl + i * 16;
      s16x4 o;
      o.x = tile[cb + 0][rr]; o.y = tile[cb + 1][rr];
      o.z = tile[cb + 2][rr]; o.w = tile[cb + 3][rr];
      *(s16x4*)(d + (long)(c0 + rr) * E_DIM + r0 + cb) = o;
    }
  }
}

// ============================================================================
// PV GEMM, load-balanced (round-5 core, epilogue now computes the suffix
// constant from psum directly): out[q-tile rt (128 rows), h-tile ct (256)] =
//   P[rt-rows, 0:(rt+1)*128] @ vT^T + sum_{j>rt} psum[j][col].
// 512 threads = 8 waves (2M x 4N), per-wave 64x64. Single-buffer BK=64.
// Grid dim3(256,2): rt = 15-(lin>>5) heavy-first -> LPT pairing, 34 K-tiles/CU.
// ============================================================================
__global__ __launch_bounds__(512, 2) void gemm_pv(
    const short* __restrict__ Pg, const short* __restrict__ Vg,
    float* __restrict__ Cg, const float* __restrict__ psum)
{
  __shared__ __align__(16) short lds[24576];  // A: [0,8192) | B: [8192,24576)

  const int t = threadIdx.x;
  const int lane = t & 63, wave = t >> 6;
  const int wm = wave >> 2, wn = wave & 3;
  const int l16 = lane & 15, kg = lane >> 4;

  const int lin = blockIdx.x + 256 * blockIdx.y;
  const int rt = 15 - (lin >> 5);          // 15..0, heavy-first
  const int rem = lin & 31;
  const int ct = rem >> 2, bz = rem & 3;

  const int K = T_DIM, N = H_DIM;
  const short* A  = Pg + (long)bz * T_DIM * T_DIM + (long)rt * 128 * K;
  const short* Bv = Vg + (long)bz * H_DIM * T_DIM + (long)ct * 256 * K;
  const int NT = (rt + 1) * 2;             // K-tiles of 64

  const int fA = t >> 3, cA = (t & 7) ^ (fA & 7);
  const long sA0 = (long)(2 * fA + (cA >> 2)) * K + (cA & 3) * 8;
  const int dA0 = t * 8;
  long sB[2]; int dB[2];
#pragma unroll
  for (int j = 0; j < 2; ++j) {
    const int cid = j * 512 + t;
    const int f = cid >> 3, c = (cid & 7) ^ (f & 7);
    sB[j] = (long)(2 * f + (c >> 2)) * K + (c & 3) * 8;
    dB[j] = cid * 8;
  }

  const int fl = l16 >> 1;
  const int slot = (((l16 & 1) * 4 + kg) ^ fl) & 7;
  const int abase = (wm * 32 + fl) * 64 + slot * 8;          // A kh-region off
  const int bbase = 8192 + (wn * 32 + fl) * 64 + slot * 8;   // B kh0 base

  f32x4 acc[4][4] = {};

  for (int tt = 0; tt < NT; ++tt) {
    const long k0 = (long)tt * 64;
    __syncthreads();  // all waves done reading previous tile
    gload16(A  + sA0   + k0,      &lds[dA0]);                  // A kh0
    gload16(A  + sA0   + k0 + 32, &lds[4096 + dA0]);           // A kh1
    gload16(Bv + sB[0] + k0,      &lds[8192 + dB[0]]);         // B kh0
    gload16(Bv + sB[1] + k0,      &lds[8192 + dB[1]]);
    gload16(Bv + sB[0] + k0 + 32, &lds[16384 + dB[0]]);        // B kh1
    gload16(Bv + sB[1] + k0 + 32, &lds[16384 + dB[1]]);
    __syncthreads();  // implicit vmcnt(0): staged data landed
#pragma unroll
    for (int kk = 0; kk < 2; ++kk) {
      bf16x8 bfr[4];
#pragma unroll
      for (int ni = 0; ni < 4; ++ni)
        bfr[ni] = *(const bf16x8*)&lds[bbase + kk * 8192 + ni * 512];
#pragma unroll
      for (int mi = 0; mi < 4; ++mi) {
        const bf16x8 a = *(const bf16x8*)&lds[abase + kk * 4096 + mi * 512];
#pragma unroll
        for (int ni = 0; ni < 4; ++ni)
          acc[mi][ni] = __builtin_amdgcn_mfma_f32_16x16x32_bf16(a, bfr[ni], acc[mi][ni], 0, 0, 0);
      }
    }
  }

  // epilogue: fp32 stores (64B segments per l16 group) + on-the-fly suffix
  float* C = Cg + (long)bz * T_DIM * H_DIM;
  const float* ps = psum + (long)bz * 16 * N;
  const int rowb = rt * 128 + wm * 64 + kg * 4;
  const int colb = ct * 256 + wn * 64 + l16;
#pragma unroll
  for (int mi = 0; mi < 4; ++mi)
#pragma unroll
    for (int ni = 0; ni < 4; ++ni) {
      const int col = colb + ni * 16;
      float s = 0.f;
      for (int j = rt + 1; j < 16; ++j)  // uniform bound: no divergence
        s += ps[(long)j * N + col];
#pragma unroll
      for (int r = 0; r < 4; ++r)
        C[(long)(rowb + mi * 16 + r) * N + col] = acc[mi][ni][r] + s;
    }
}

// ============================================================================
// 256x256-tile 8-phase GEMM (round-3 structure) — used for the projection.
// Refcheck'd rounds 3-5; unchanged.
// ============================================================================
template<int MODE>
__global__ __launch_bounds__(512, 2) void gemm256(
    const short* __restrict__ Ag, const short* __restrict__ Bg,
    const float* __restrict__ bias, const float* __restrict__ bias2,
    void* __restrict__ Cg, void* __restrict__ Cg2,
    int N, int K, long sA, long sB)
{
  __shared__ __align__(16) short lds[2 * 32768];  // 128 KiB

  const int t = threadIdx.x;
  const int lane = t & 63, wave = t >> 6;
  const int wm = wave >> 2, wn = wave & 3;
  const int l16 = lane & 15, kg = lane >> 4;

  int rt, ct;
  {
    // bijective XCD swizzle (nwg = 512, divisible by 8)
    int lin = blockIdx.y * gridDim.x + blockIdx.x;
    const int cpx = (gridDim.x * gridDim.y) >> 3;
    lin = (lin & 7) * cpx + (lin >> 3);
    rt = lin / gridDim.x; ct = lin - rt * gridDim.x;
  }

  const short* A  = Ag + (long)rt * 256 * K;
  const short* Bp = Bg + (long)ct * 256 * K;
  const int NT = K >> 6;  // K-tiles of 64

  long soff[2];
  int dsto[2];
#pragma unroll
  for (int j = 0; j < 2; ++j) {
    const int cid = j * 512 + t;
    const int f = cid >> 3, sl = cid & 7;
    const int c = sl ^ (f & 7);
    soff[j] = (long)(2 * f + (c >> 2)) * K + (c & 3) * 8;
    dsto[j] = cid * 8;
  }

  const int fl = l16 >> 1;
  const int slot = (((l16 & 1) * 4 + kg) ^ fl) & 7;
  const int aoff = (wm * 64 + fl) * 64 + slot * 8;   // within A K-half
  const int boff = (wn * 32 + fl) * 64 + slot * 8;   // within B K-half

  f32x4 acc[8][4] = {};

  // prologue: stage tile 0 fully
  {
    short* S = lds;
#pragma unroll
    for (int kh = 0; kh < 2; ++kh)
#pragma unroll
      for (int j = 0; j < 2; ++j) {
        gload16(A  + soff[j] + kh * 32, &S[kh * 8192 + dsto[j]]);
        gload16(Bp + soff[j] + kh * 32, &S[16384 + kh * 8192 + dsto[j]]);
      }
  }
  asm volatile("s_waitcnt vmcnt(4)");  // kh0 pair landed
  __builtin_amdgcn_sched_barrier(0);
  bar();

  for (int T = 0; T < NT; ++T) {
    const short* Abase = lds + (T & 1) * 32768;
    short* S = lds + ((T + 1) & 1) * 32768;
    const long kIss = (long)(T + 1) * 64;
    const bool st = (T + 1) < NT;
    bf16x8 bfr[4], af[4];

    // ---- phase s=0: kh0, m0-3 ----
    {
      const short* Ab = Abase;
      const short* Bb = Abase + 16384;
#pragma unroll
      for (int n = 0; n < 4; ++n) bfr[n] = *(const bf16x8*)&Bb[boff + n * 512];
#pragma unroll
      for (int m = 0; m < 4; ++m) af[m] = *(const bf16x8*)&Ab[aoff + m * 512];
      if (st) {
        gload16(A + soff[0] + kIss, &S[dsto[0]]);
        gload16(A + soff[1] + kIss, &S[dsto[1]]);
      }
      bar();
      __builtin_amdgcn_s_setprio(1);
#pragma unroll
      for (int m = 0; m < 4; ++m)
#pragma unroll
        for (int n = 0; n < 4; ++n)
          acc[m][n] = __builtin_amdgcn_mfma_f32_16x16x32_bf16(af[m], bfr[n], acc[m][n], 0, 0, 0);
      __builtin_amdgcn_s_setprio(0);
      bar();
    }
    // ---- phase s=1: kh0, m4-7 ----
    {
      const short* Ab = Abase;
#pragma unroll
      for (int m = 0; m < 4; ++m) af[m] = *(const bf16x8*)&Ab[aoff + (m + 4) * 512];
      if (st) {
        gload16(Bp + soff[0] + kIss, &S[16384 + dsto[0]]);
        gload16(Bp + soff[1] + kIss, &S[16384 + dsto[1]]);
      }
      bar();
      __builtin_amdgcn_s_setprio(1);
#pragma unroll
      for (int m = 0; m < 4; ++m)
#pragma unroll
        for (int n = 0; n < 4; ++n)
          acc[m + 4][n] = __builtin_amdgcn_mfma_f32_16x16x32_bf16(af[m], bfr[n], acc[m + 4][n], 0, 0, 0);
      __builtin_amdgcn_s_setprio(0);
      if (T == NT - 1) asm volatile("s_waitcnt vmcnt(0)");
      else             asm volatile("s_waitcnt vmcnt(4)");
      __builtin_amdgcn_sched_barrier(0);
      bar();
    }
    // ---- phase s=2: kh1, m0-3 ----
    {
      const short* Ab = Abase + 8192;
      const short* Bb = Abase + 16384 + 8192;
#pragma unroll
      for (int n = 0; n < 4; ++n) bfr[n] = *(const bf16x8*)&Bb[boff + n * 512];
#pragma unroll
      for (int m = 0; m < 4; ++m) af[m] = *(const bf16x8*)&Ab[aoff + m * 512];
      if (st) {
        gload16(A + soff[0] + kIss + 32, &S[8192 + dsto[0]]);
        gload16(A + soff[1] + kIss + 32, &S[8192 + dsto[1]]);
      }
      bar();
      __builtin_amdgcn_s_setprio(1);
#pragma unroll
      for (int m = 0; m < 4; ++m)
#pragma unroll
        for (int n = 0; n < 4; ++n)
          acc[m][n] = __builtin_amdgcn_mfma_f32_16x16x32_bf16(af[m], bfr[n], acc[m][n], 0, 0, 0);
      __builtin_amdgcn_s_setprio(0);
      bar();
    }
    // ---- phase s=3: kh1, m4-7 ----
    {
      const short* Ab = Abase + 8192;
#pragma unroll
      for (int m = 0; m < 4; ++m) af[m] = *(const bf16x8*)&Ab[aoff + (m + 4) * 512];
      if (st) {
        gload16(Bp + soff[0] + kIss + 32, &S[16384 + 8192 + dsto[0]]);
        gload16(Bp + soff[1] + kIss + 32, &S[16384 + 8192 + dsto[1]]);
      }
      bar();
      __builtin_amdgcn_s_setprio(1);
#pragma unroll
      for (int m = 0; m < 4; ++m)
#pragma unroll
        for (int n = 0; n < 4; ++n)
          acc[m + 4][n] = __builtin_amdgcn_mfma_f32_16x16x32_bf16(af[m], bfr[n], acc[m + 4][n], 0, 0, 0);
      __builtin_amdgcn_s_setprio(0);
      if (st) {
        asm volatile("s_waitcnt vmcnt(4)");
        __builtin_amdgcn_sched_barrier(0);
      }
      bar();
    }
  }

  __syncthreads();  // full drain before LDS reuse

  // repack to bf16 in LDS (256x256 = 128 KiB), row-XOR swizzle
  {
    short* Cs = lds;
    const int Nh = N >> 1;
#pragma unroll
    for (int m = 0; m < 8; ++m)
#pragma unroll
      for (int n = 0; n < 4; ++n) {
        const int cl = wn * 64 + n * 16 + l16;
        const int colg = ct * 256 + cl;
        const float bv = (colg < Nh) ? bias[colg] : bias2[colg - Nh];
#pragma unroll
        for (int r = 0; r < 4; ++r) {
          const int rl = wm * 128 + m * 16 + kg * 4 + r;
          *(short*)((char*)Cs + (((((rl << 8) + cl) << 1)) ^ ((rl & 7) << 4))) =
              f2bf(acc[m][n][r] + bv);
        }
      }
    __syncthreads();
    short* C = ((ct * 256) < Nh) ? (short*)Cg : (short*)Cg2;
    const int rr = t >> 1, hc = (t & 1) * 128;
    const long gbase = (long)(rt * 256 + rr) * Nh + ((ct * 256) & (Nh - 1)) + hc;
#pragma unroll
    for (int j = 0; j < 16; ++j)
      *(bf16x8*)(C + gbase + j * 8) =
          *(const bf16x8*)((const char*)Cs +
              ((((rr << 8) + hc + (j << 3)) << 1) ^ ((rr & 7) << 4)));
  }
}

// ============================================================================
// verified 128^2 kernel, scores pass: E = exp(mask(q q^T)*scale) lower tiles
// + column sums (diag tile seeds the skipped-upper-blocks constant 128*ct).
// ============================================================================
__global__ __launch_bounds__(256) void gemm_sc(
    const short* __restrict__ Ag, short* __restrict__ Cg,
    float* __restrict__ colsum, int K, float scale)
{
  __shared__ __align__(16) short lds[128 * 64 * 2];  // As | Bs; reused as Cs
  short* As = lds;
  short* Bs = lds + 128 * 64;
  __shared__ float csum[128];

  const int t = threadIdx.x;
  const int bz = blockIdx.z;
  const int M = T_DIM, N = T_DIM;

  int rt, ct;
  {
    int idx = 135 - blockIdx.x;  // heavy (large-rt) tiles dispatch first
    rt = (int)((sqrtf(8.0f * idx + 1.0f) - 1.0f) * 0.5f);
    while ((rt + 1) * (rt + 2) / 2 <= idx) rt++;
    while (rt * (rt + 1) / 2 > idx) rt--;
    ct = idx - rt * (rt + 1) / 2;
  }

  const short* A = Ag + (long)bz * T_DIM * H_DIM + (long)rt * 128 * K;
  const short* B = Ag + (long)bz * T_DIM * H_DIM + (long)ct * 128 * K;

  const int lane = t & 63;
  const int wave = t >> 6;
  const int wr = wave >> 1, wc = wave & 1;
  const int l16 = lane & 15, kg = lane >> 4;

  if (t < 128) csum[t] = (rt == ct) ? 128.0f * ct : 0.0f;

  f32x4 acc[4][4] = {};

  for (int k0 = 0; k0 < K; k0 += 64) {
    __syncthreads();
#pragma unroll
    for (int j = 0; j < 4; ++j) {
      const int e = j * 256 + t;
      const int r = e >> 3, cl = e & 7;
      const int cg = cl ^ (r & 7);
      gload16(A + (long)r * K + (k0 + cg * 8), &As[e * 8]);
      gload16(B + (long)r * K + (k0 + cg * 8), &Bs[e * 8]);
    }
    __syncthreads();
#pragma unroll
    for (int kk = 0; kk < 2; ++kk) {
      bf16x8 af[4], bfr[4];
#pragma unroll
      for (int mi = 0; mi < 4; ++mi)
        af[mi] = *(const bf16x8*)&As[(wr * 64 + mi * 16 + l16) * 64 +
                                     ((kk * 4 + kg) ^ (l16 & 7)) * 8];
#pragma unroll
      for (int ni = 0; ni < 4; ++ni)
        bfr[ni] = *(const bf16x8*)&Bs[(wc * 64 + ni * 16 + l16) * 64 +
                                      ((kk * 4 + kg) ^ (l16 & 7)) * 8];
#pragma unroll
      for (int mi = 0; mi < 4; ++mi)
#pragma unroll
        for (int ni = 0; ni < 4; ++ni)
          acc[mi][ni] = __builtin_amdgcn_mfma_f32_16x16x32_bf16(af[mi], bfr[ni], acc[mi][ni], 0, 0, 0);
    }
  }

  {
    short* Cs = lds;  // 128x128 bf16 tile
    __syncthreads();
    float ps[4] = {0.f, 0.f, 0.f, 0.f};
#pragma unroll
    for (int mi = 0; mi < 4; ++mi)
#pragma unroll
      for (int ni = 0; ni < 4; ++ni) {
        const int cl = wc * 64 + ni * 16 + l16;
        const int col = ct * 128 + cl;
#pragma unroll
        for (int r = 0; r < 4; ++r) {
          const int rl = wr * 64 + kg * 4 + mi * 16 + r;
          const int row = rt * 128 + rl;
          float e = (row >= col) ? __expf(acc[mi][ni][r] * scale) : 1.0f;
          Cs[rl * 128 + cl] = f2bf(e);
          ps[ni] += e;
        }
      }
#pragma unroll
    for (int ni = 0; ni < 4; ++ni)
      atomicAdd(&csum[wc * 64 + ni * 16 + l16], ps[ni]);
    __syncthreads();
    short* C = Cg + (long)bz * T_DIM * T_DIM;
    const int rr = t >> 1, cc = (t & 1) * 64;
    const long gbase = (long)(rt * 128 + rr) * N + ct * 128 + cc;
#pragma unroll
    for (int j = 0; j < 8; ++j)
      *(bf16x8*)(C + gbase + j * 8) = *(const bf16x8*)&Cs[rr * 128 + cc + j * 8];
    if (t < 128)
      atomicAdd(&colsum[(long)bz * N + ct * 128 + t], csum[t]);
  }
}

// vT[h][k] = v[k][h] / sums[k]  (bf16 [T,H] -> bf16 [H,T], per batch z)
// + psum[bz][r0>>7][h] += sum over this block's 64 keys of v[k][h]/sums[k]
//   (LDS column-reduce, one global atomicAdd per column — replaces block_psum)
__global__ __launch_bounds__(256) void vtrans(
    const short* __restrict__ src, short* __restrict__ dst,
    const float* __restrict__ sums, float* __restrict__ psum)
{
  __shared__ short tile[64][65];
  __shared__ float cacc[64];
  const int t = threadIdx.x;
  const int c0 = blockIdx.x * 64;   // over H
  const int r0 = blockIdx.y * 64;   // over T (keys)
  const int bz = blockIdx.z;
  const short* s = src + (long)bz * T_DIM * H_DIM;
  short* d = dst + (long)bz * H_DIM * T_DIM;
  const float* su = sums + (long)bz * T_DIM;
  const int rl = t >> 4, cb = (t & 15) * 4;
  if (t < 64) cacc[t] = 0.f;
  float p4[4] = {0.f, 0.f, 0.f, 0.f};
#pragma unroll
  for (int i = 0; i < 4; ++i) {
    int r = rl + i * 16;
    const float rs = 1.0f / su[r0 + r];
    const s16x4 w = *(const s16x4*)(s + (long)(r0 + r) * H_DIM + c0 + cb);
    const float f0 = bf2f(w.x) * rs, f1 = bf2f(w.y) * rs;
    const float f2 = bf2f(w.z) * rs, f3 = bf2f(w.w) * rs;
    tile[r][cb + 0] = f2bf(f0); tile[r][cb + 1] = f2bf(f1);
    tile[r][cb + 2] = f2bf(f2); tile[r][cb + 3] = f2bf(f3);
    p4[0] += f0; p4[1] += f1; p4[2] += f2; p4[3] += f3;
  }
  __syncthreads();  // tile ready; cacc zero-init ordered before atomics
#pragma unroll
  for (int j = 0; j < 4; ++j) atomicAdd(&cacc[cb + j], p4[j]);
#pragma unroll
  for (int i = 0; i < 4; ++i) {
    int rr = rl + i * 16;
    s16x4 o;
    o.x = tile[cb + 0][rr]; o.y = tile[cb + 1][rr];
    o.z = tile[cb + 2][rr]; o.w = tile[cb + 3][rr];
    *(s16x4*)(d + (long)(c0 + rr) * T_DIM + r0 + cb) = o;
  }
  __syncthreads();  // cacc complete
  if (t < 64)
    atomicAdd(&psum[((long)bz * 16 + (r0 >> 7)) * H_DIM + c0 + t], cacc[t]);
}

extern "C" void kernel_launch(void* const* d_in, const int* in_sizes, int n_in,
                              void* d_out, int out_size, void* d_ws, size_t ws_size,
                              hipStream_t stream) {
  const float* x  = (const float*)d_in[0];
  const float* Wq = (const float*)d_in[1];
  const float* bq = (const float*)d_in[2];
  const float* Wv = (const float*)d_in[3];
  const float* bv = (const float*)d_in[4];
  float* out = (float*)d_out;

  // d_ws layout (96 MiB + 544 KiB)
  char* ws = (char*)d_ws;
  short* P      = (short*)(ws);                                   // 32 MiB [B][T][T]
  short* q      = (short*)(ws + (size_t)32 * 1024 * 1024);        // 32 MiB [B*T][H]
  short* v      = (short*)(ws + (size_t)64 * 1024 * 1024);        // 32 MiB [B*T][H]
  float* colsum = (float*)(ws + (size_t)96 * 1024 * 1024);        // 32 KiB [B][T]
  float* psum   = (float*)(ws + (size_t)96 * 1024 * 1024 + 32 * 1024);  // 512 KiB [B][16][H]
  short* vT = q;  // alias: q dead after the scores GEMM

  // d_out (64 MiB) doubles as scratch; all dead before PV GEMM writes d_out.
  short* xb    = (short*)d_out;                                     // 16 MiB [B*T][E]
  short* WqvT  = (short*)((char*)d_out + (size_t)16 * 1024 * 1024); //  8 MiB [2H][E]

  const float scale = 0.022097086912079612f;  // 1/sqrt(2048)

  // x -> bf16 | Wq,Wv -> transposed bf16 [2H][E] | zero colsum+psum (1 launch)
  prep<<<dim3(NCONV + 1024), dim3(256), 0, stream>>>(
      x, xb, Wq, Wv, WqvT, colsum, psum);

  // fused projections: [q | v] = x @ WqvT^T + [bq | bv]  (M=8192, N=4096, K=1024)
  gemm256<0><<<dim3((2 * H_DIM) / 256, (B_DIM * T_DIM) / 256, 1), dim3(512), 0, stream>>>(
      xb, WqvT, bq, bv, q, v, 2 * H_DIM, E_DIM, 0, 0);

  // E = exp(mask(q q^T)/sqrt(H)): lower-triangular 128-tiles + colsum
  gemm_sc<<<dim3(136, 1, B_DIM), dim3(256), 0, stream>>>(
      q, P, colsum, H_DIM, scale);

  // vT[h][k] = v[k][h] / colsum[k]; fused psum column-sums
  vtrans<<<dim3(H_DIM / 64, T_DIM / 64, B_DIM), dim3(256), 0, stream>>>(
      v, vT, colsum, psum);

  // out = P(:, :(rt+1)*128) @ v' + suffix(psum): 512 balanced jobs (34 Kt/CU)
  gemm_pv<<<dim3(256, 2, 1), dim3(512), 0, stream>>>(P, vT, out, psum);
}